// Round 1
// 442.802 us; speedup vs baseline: 1.0526x; 1.0526x over previous
//
#include <hip/hip_runtime.h>
#include <hip/hip_bf16.h>
#include <math.h>

// Problem dims (fixed by the reference)
#define PB 8
#define PS 4096
#define PD 1024

typedef __attribute__((ext_vector_type(8))) short bf16x8;
typedef __attribute__((ext_vector_type(4))) float f32x4;

__device__ __forceinline__ ushort f2b(float f) {
    // round-to-nearest-even f32 -> bf16
    unsigned u = __float_as_uint(f);
    unsigned r = (u + 0x7FFFu + ((u >> 16) & 1u)) >> 16;
    return (ushort)r;
}
__device__ __forceinline__ float b2f(ushort h) {
    return __uint_as_float(((unsigned)h) << 16);
}

__device__ __forceinline__ void gl2lds16(const void* g, void* l) {
    // async global->LDS, 16B/lane; LDS dest is wave-uniform base + lane*16
    __builtin_amdgcn_global_load_lds(
        (const __attribute__((address_space(1))) void*)g,
        (__attribute__((address_space(3))) void*)l, 16, 0, 0);
}

__global__ __launch_bounds__(256) void cvt_f32_bf16(const float* __restrict__ in,
                                                    ushort* __restrict__ out, int n) {
    int i = (blockIdx.x * 256 + threadIdx.x) * 4;
    if (i + 3 < n) {
        float4 v = *(const float4*)(in + i);
        ushort4 o;
        o.x = f2b(v.x); o.y = f2b(v.y); o.z = f2b(v.z); o.w = f2b(v.w);
        *(ushort4*)(out + i) = o;
    }
}

// both weight matrices in one dispatch
__global__ __launch_bounds__(256) void cvt_w2(const float* __restrict__ Wu,
                                              const float* __restrict__ Wf,
                                              ushort* __restrict__ Wub,
                                              ushort* __restrict__ Wfb, int n) {
    int i = (blockIdx.x * 256 + threadIdx.x) * 4;
    const float* in = (i < n) ? Wu : Wf;
    ushort* out = (i < n) ? Wub : Wfb;
    int j = (i < n) ? i : i - n;
    float4 v = *(const float4*)(in + j);
    ushort4 o;
    o.x = f2b(v.x); o.y = f2b(v.y); o.z = f2b(v.z); o.w = f2b(v.w);
    *(ushort4*)(out + j) = o;
}

// C = A (MxK, row-major bf16) * Bm^T (Bm is NxK row-major bf16) + bias
//
// 256x256 block tile, BK=64, 512 threads = 8 waves (2M x 4N), per-wave 128x64
// output (acc[8][4] 16x16 fragments). LDS: 2 slots x (A 256x64 + B 256x64)
// bf16 = 128 KiB, 1 block/CU.
//
// Deep pipeline with counted vmcnt (never drains in steady state):
//   prologue: issue tiles 0,1 (8 lines each); vmcnt(8); barrier  -> tile 0 landed
//   iter t:   compute tile t (2 k-half phases, 64 MFMA/wave)
//             lgkmcnt(0); barrier            -> slot t&1 free for reuse
//             issue tile t+2 into slot t&1 (8 lines)
//             vmcnt(8)                       -> tile t+1 landed, t+2 in flight
//             barrier
// Tile t+2's loads fly across a full iteration of MFMA before being waited on.
//
// LDS rows are 64 elems (128 B); granule g of row r holds logical granule
// g^(r&7) (swizzle applied on the GLOBAL address side of the DMA; LDS side
// must stay linear). Verified conflict-free in prior rounds (SQ_LDS_BANK_CONFLICT=0).
template <bool OUT_BF16>
__global__ __launch_bounds__(512, 2) void gemm_bt(const ushort* __restrict__ A,
                                                  const ushort* __restrict__ Bm,
                                                  const float* __restrict__ bias,
                                                  void* __restrict__ C,
                                                  int M, int N, int K) {
    __shared__ ushort As[2][256 * 64];   // 2 x 32 KB
    __shared__ ushort Bs[2][256 * 64];   // 2 x 32 KB

    const int tid = threadIdx.x;
    const int lane = tid & 63;
    const int wave = tid >> 6;                 // 0..7
    const int nbn = N >> 8;                    // 4
    // XCD-aware mapping: XCD = blockIdx % 8; each XCD owns contiguous bm range,
    // bn fastest -> A panel (512 KB) L2-hit across 4 consecutive blocks; whole
    // B (2 MB) stays L2-resident per XCD.
    const int xcd = blockIdx.x & 7;
    const int g = blockIdx.x >> 3;
    const int bpx = (gridDim.x >> 3) / nbn;    // bm tiles per xcd
    const int bm = xcd * bpx + g / nbn;
    const int bn = g % nbn;
    const int wm = wave >> 2, wn = wave & 3;   // 2 x 4 wave grid
    const int l15 = lane & 15, quad = lane >> 4;

    // staging: per line (64 rows), wave w covers rows rb*64 + w*8 + (lane>>3),
    // slot granule lane&7; fetch logical granule (lane&7)^(row&7).
    const int srow = wave * 8 + (lane >> 3);
    const int sgx = ((lane & 7) ^ ((lane >> 3) & 7)) * 8;
    const ushort* Ag = A + (size_t)(bm * 256 + srow) * K + sgx;
    const ushort* Bg = Bm + (size_t)(bn * 256 + srow) * K + sgx;
    const int lbase = wave * 8 * 64;           // wave-uniform LDS base (elems)

#define STAGE_TILE(kk, cc)                                                      \
    do {                                                                        \
        _Pragma("unroll")                                                       \
        for (int rb = 0; rb < 4; ++rb) {                                        \
            gl2lds16(Ag + (kk) + (size_t)(rb * 64) * K, &As[cc][rb * 4096 + lbase]); \
            gl2lds16(Bg + (kk) + (size_t)(rb * 64) * K, &Bs[cc][rb * 4096 + lbase]); \
        }                                                                       \
    } while (0)

    f32x4 acc[8][4];
#pragma unroll
    for (int i = 0; i < 8; ++i)
#pragma unroll
        for (int j = 0; j < 4; ++j) acc[i][j] = (f32x4){0.f, 0.f, 0.f, 0.f};

    const int nt = K >> 6;   // 16

    // prologue: tiles 0 and 1 in flight; wait for tile 0 only
    STAGE_TILE(0, 0);
    STAGE_TILE(64, 1);
    asm volatile("s_waitcnt vmcnt(8)" ::: "memory");
    __builtin_amdgcn_s_barrier();

    for (int t = 0; t < nt; ++t) {
        const int c = t & 1;
        const ushort* Ab = &As[c][(wm * 128 + l15) * 64];
        const ushort* Bb = &Bs[c][(wn * 64 + l15) * 64];
#pragma unroll
        for (int p = 0; p < 2; ++p) {
            // logical k-granule = p*4 + quad; slot = logical ^ (row&7)
            const int aoff = ((p * 4 + quad) ^ (l15 & 7)) * 8;
            bf16x8 af[8], bfr[4];
#pragma unroll
            for (int i = 0; i < 8; ++i)
                af[i] = *(const bf16x8*)(Ab + i * 16 * 64 + aoff);
#pragma unroll
            for (int j = 0; j < 4; ++j)
                bfr[j] = *(const bf16x8*)(Bb + j * 16 * 64 + aoff);
            __builtin_amdgcn_s_setprio(1);
#pragma unroll
            for (int i = 0; i < 8; ++i)
#pragma unroll
                for (int j = 0; j < 4; ++j)
                    acc[i][j] = __builtin_amdgcn_mfma_f32_16x16x32_bf16(af[i], bfr[j], acc[i][j], 0, 0, 0);
            __builtin_amdgcn_s_setprio(0);
        }
        // all this wave's ds_reads complete -> after barrier, slot c is reusable
        asm volatile("s_waitcnt lgkmcnt(0)" ::: "memory");
        __builtin_amdgcn_s_barrier();
        if (t + 2 < nt) {
            STAGE_TILE((t + 2) * 64, c);
            // tile t+1 (issued last iteration) landed; t+2's 8 lines stay in flight
            asm volatile("s_waitcnt vmcnt(8)" ::: "memory");
        } else {
            asm volatile("s_waitcnt vmcnt(0)" ::: "memory");
        }
        __builtin_amdgcn_s_barrier();
    }
#undef STAGE_TILE

    // epilogue: C/D layout col=lane&15, row=quad*4+reg  [verified m89/m91]
    const int gm0 = bm * 256 + wm * 128;
    const int gn0 = bn * 256 + wn * 64;
    float bv[4];
#pragma unroll
    for (int j = 0; j < 4; ++j) bv[j] = bias[gn0 + j * 16 + l15];
#pragma unroll
    for (int i = 0; i < 8; ++i) {
#pragma unroll
        for (int j = 0; j < 4; ++j) {
            const int col = gn0 + j * 16 + l15;
#pragma unroll
            for (int r = 0; r < 4; ++r) {
                const int row = gm0 + i * 16 + quad * 4 + r;
                float v = acc[i][j][r] + bv[j];
                if (OUT_BF16)
                    ((ushort*)C)[(size_t)row * N + col] = f2b(v);
                else
                    ((float*)C)[(size_t)row * N + col] = v;
            }
        }
    }
}

// Pass A: per (b, chunk) compute affine (A_c scalar, B_c vector of D)
// 4-step batched loads so 4+ ushort4 loads are in flight per wave.
__global__ __launch_bounds__(256) void scan_partial(const ushort* __restrict__ upd,
                                                    const float* __restrict__ mask,
                                                    const float* __restrict__ dp,
                                                    float* __restrict__ Bc,
                                                    float* __restrict__ Ac,
                                                    int S, int D, int C) {
    const int c = blockIdx.x % C;
    const int b = blockIdx.x / C;
    const int L = S / C;
    const int d0 = threadIdx.x * 4;
    const float decay = 1.f / (1.f + expf(-dp[0]));
    const ushort* up = upd + ((size_t)b * S + (size_t)c * L) * D + d0;
    const float* mp = mask + (size_t)b * S + (size_t)c * L;
    float aA = 1.f;
    float b0 = 0.f, b1 = 0.f, b2 = 0.f, b3 = 0.f;
    for (int s0 = 0; s0 < L; s0 += 4) {
        float4 mv = *(const float4*)(mp + s0);
        ushort4 u0 = *(const ushort4*)(up + (size_t)(s0 + 0) * D);
        ushort4 u1 = *(const ushort4*)(up + (size_t)(s0 + 1) * D);
        ushort4 u2 = *(const ushort4*)(up + (size_t)(s0 + 2) * D);
        ushort4 u3 = *(const ushort4*)(up + (size_t)(s0 + 3) * D);
        float m, a;
        m = mv.x; a = m * decay + (1.f - m); aA *= a;
        b0 = a * b0 + m * b2f(u0.x); b1 = a * b1 + m * b2f(u0.y);
        b2 = a * b2 + m * b2f(u0.z); b3 = a * b3 + m * b2f(u0.w);
        m = mv.y; a = m * decay + (1.f - m); aA *= a;
        b0 = a * b0 + m * b2f(u1.x); b1 = a * b1 + m * b2f(u1.y);
        b2 = a * b2 + m * b2f(u1.z); b3 = a * b3 + m * b2f(u1.w);
        m = mv.z; a = m * decay + (1.f - m); aA *= a;
        b0 = a * b0 + m * b2f(u2.x); b1 = a * b1 + m * b2f(u2.y);
        b2 = a * b2 + m * b2f(u2.z); b3 = a * b3 + m * b2f(u2.w);
        m = mv.w; a = m * decay + (1.f - m); aA *= a;
        b0 = a * b0 + m * b2f(u3.x); b1 = a * b1 + m * b2f(u3.y);
        b2 = a * b2 + m * b2f(u3.z); b3 = a * b3 + m * b2f(u3.w);
    }
    *(float4*)(Bc + (size_t)blockIdx.x * D + d0) = make_float4(b0, b1, b2, b3);
    if (threadIdx.x == 0) Ac[blockIdx.x] = aA;
}

// Pass B: serial prefix over C chunks per (b,d) chain; writes incoming state per chunk.
// Unrolled x4 with independent Bc loads prefetched ahead of the dependent chain.
__global__ __launch_bounds__(256) void scan_prefix(const float* __restrict__ Ac,
                                                   const float* __restrict__ Bc,
                                                   float* __restrict__ Mn, int D, int C) {
    int gid = blockIdx.x * 256 + threadIdx.x;  // over B*D
    int b = gid / D;
    int d = gid - b * D;
    float mem = 0.f;
    for (int c = 0; c < C; c += 4) {
        float4 av = *(const float4*)(Ac + b * C + c);
        size_t i0 = ((size_t)(b * C + c)) * D + d;
        float q0 = Bc[i0];
        float q1 = Bc[i0 + D];
        float q2 = Bc[i0 + 2 * (size_t)D];
        float q3 = Bc[i0 + 3 * (size_t)D];
        Mn[i0] = mem;                    mem = av.x * mem + q0;
        Mn[i0 + D] = mem;                mem = av.y * mem + q1;
        Mn[i0 + 2 * (size_t)D] = mem;    mem = av.z * mem + q2;
        Mn[i0 + 3 * (size_t)D] = mem;    mem = av.w * mem + q3;
    }
}

// Pass C: replay each chunk from its incoming state, write mem_seq (bf16)
__global__ __launch_bounds__(256) void scan_final(const ushort* __restrict__ upd,
                                                  const float* __restrict__ mask,
                                                  const float* __restrict__ dp,
                                                  const float* __restrict__ Mn,
                                                  ushort* __restrict__ ms,
                                                  int S, int D, int C) {
    const int c = blockIdx.x % C;
    const int b = blockIdx.x / C;
    const int L = S / C;
    const int d0 = threadIdx.x * 4;
    const float decay = 1.f / (1.f + expf(-dp[0]));
    const ushort* up = upd + ((size_t)b * S + (size_t)c * L) * D + d0;
    ushort* op = ms + ((size_t)b * S + (size_t)c * L) * D + d0;
    const float* mp = mask + (size_t)b * S + (size_t)c * L;
    float4 m0 = *(const float4*)(Mn + (size_t)blockIdx.x * D + d0);
    float v0 = m0.x, v1 = m0.y, v2 = m0.z, v3 = m0.w;
    for (int s0 = 0; s0 < L; s0 += 4) {
        float4 mv = *(const float4*)(mp + s0);
        ushort4 u0 = *(const ushort4*)(up + (size_t)(s0 + 0) * D);
        ushort4 u1 = *(const ushort4*)(up + (size_t)(s0 + 1) * D);
        ushort4 u2 = *(const ushort4*)(up + (size_t)(s0 + 2) * D);
        ushort4 u3 = *(const ushort4*)(up + (size_t)(s0 + 3) * D);
        float m, a;
        ushort4 o;
        m = mv.x; a = m * decay + (1.f - m);
        v0 = a * v0 + m * b2f(u0.x); v1 = a * v1 + m * b2f(u0.y);
        v2 = a * v2 + m * b2f(u0.z); v3 = a * v3 + m * b2f(u0.w);
        o.x = f2b(v0); o.y = f2b(v1); o.z = f2b(v2); o.w = f2b(v3);
        *(ushort4*)(op + (size_t)(s0 + 0) * D) = o;
        m = mv.y; a = m * decay + (1.f - m);
        v0 = a * v0 + m * b2f(u1.x); v1 = a * v1 + m * b2f(u1.y);
        v2 = a * v2 + m * b2f(u1.z); v3 = a * v3 + m * b2f(u1.w);
        o.x = f2b(v0); o.y = f2b(v1); o.z = f2b(v2); o.w = f2b(v3);
        *(ushort4*)(op + (size_t)(s0 + 1) * D) = o;
        m = mv.z; a = m * decay + (1.f - m);
        v0 = a * v0 + m * b2f(u2.x); v1 = a * v1 + m * b2f(u2.y);
        v2 = a * v2 + m * b2f(u2.z); v3 = a * v3 + m * b2f(u2.w);
        o.x = f2b(v0); o.y = f2b(v1); o.z = f2b(v2); o.w = f2b(v3);
        *(ushort4*)(op + (size_t)(s0 + 2) * D) = o;
        m = mv.w; a = m * decay + (1.f - m);
        v0 = a * v0 + m * b2f(u3.x); v1 = a * v1 + m * b2f(u3.y);
        v2 = a * v2 + m * b2f(u3.z); v3 = a * v3 + m * b2f(u3.w);
        o.x = f2b(v0); o.y = f2b(v1); o.z = f2b(v2); o.w = f2b(v3);
        *(ushort4*)(op + (size_t)(s0 + 3) * D) = o;
    }
}

extern "C" void kernel_launch(void* const* d_in, const int* in_sizes, int n_in,
                              void* d_out, int out_size, void* d_ws, size_t ws_size,
                              hipStream_t stream) {
    const float* x    = (const float*)d_in[0];
    const float* mask = (const float*)d_in[1];
    const float* Wu   = (const float*)d_in[2];
    const float* bu   = (const float*)d_in[3];
    const float* Wf   = (const float*)d_in[4];
    const float* bfv  = (const float*)d_in[5];
    const float* dp   = (const float*)d_in[6];

    const int B = PB, S = PS, D = PD;
    const int M = B * S;          // 32768
    const int C = 128;            // scan chunks; L = 32

    // workspace layout (bytes): total ~204 MB
    char* ws = (char*)d_ws;
    ushort* xb   = (ushort*)(ws);                 // 64 MB  bf16 x
    ushort* updb = (ushort*)(ws + 67108864);      // 64 MB  bf16 upd
    ushort* memb = (ushort*)(ws + 134217728);     // 64 MB  bf16 mem_seq
    ushort* Wub  = (ushort*)(ws + 201326592);     // 2 MB
    ushort* Wfb  = (ushort*)(ws + 203423744);     // 2 MB
    float*  Bc   = (float*)(ws + 205520896);      // 4 MB   B*C*D
    float*  Mn   = (float*)(ws + 209715200);      // 4 MB   B*C*D
    float*  Ac   = (float*)(ws + 213909504);      // 4 KB   B*C

    const int nx = B * S * D;
    cvt_f32_bf16<<<nx / 1024, 256, 0, stream>>>(x, xb, nx);
    cvt_w2<<<(2 * D * D) / 1024, 256, 0, stream>>>(Wu, Wf, Wub, Wfb, D * D);

    dim3 g1((M / 256) * (D / 256));  // 512 blocks, %8 == 0 for XCD swizzle
    gemm_bt<true><<<g1, 512, 0, stream>>>(xb, Wub, bu, (void*)updb, M, D, D);

    scan_partial<<<B * C, 256, 0, stream>>>(updb, mask, dp, Bc, Ac, S, D, C);
    scan_prefix<<<(B * D) / 256, 256, 0, stream>>>(Ac, Bc, Mn, D, C);
    scan_final<<<B * C, 256, 0, stream>>>(updb, mask, dp, Mn, memb, S, D, C);

    gemm_bt<false><<<g1, 512, 0, stream>>>(memb, Wfb, bfv, d_out, M, D, D);
}

// Round 2
// 435.405 us; speedup vs baseline: 1.0705x; 1.0170x over previous
//
#include <hip/hip_runtime.h>
#include <hip/hip_bf16.h>
#include <math.h>

// Problem dims (fixed by the reference)
#define PB 8
#define PS 4096
#define PD 1024

typedef __attribute__((ext_vector_type(8))) short bf16x8;
typedef __attribute__((ext_vector_type(4))) float f32x4;

__device__ __forceinline__ ushort f2b(float f) {
    // round-to-nearest-even f32 -> bf16
    unsigned u = __float_as_uint(f);
    unsigned r = (u + 0x7FFFu + ((u >> 16) & 1u)) >> 16;
    return (ushort)r;
}
__device__ __forceinline__ float b2f(ushort h) {
    return __uint_as_float(((unsigned)h) << 16);
}

__device__ __forceinline__ void gl2lds16(const void* g, void* l) {
    // async global->LDS, 16B/lane; LDS dest is wave-uniform base + lane*16
    __builtin_amdgcn_global_load_lds(
        (const __attribute__((address_space(1))) void*)g,
        (__attribute__((address_space(3))) void*)l, 16, 0, 0);
}

__global__ __launch_bounds__(256) void cvt_f32_bf16(const float* __restrict__ in,
                                                    ushort* __restrict__ out, int n) {
    int i = (blockIdx.x * 256 + threadIdx.x) * 4;
    if (i + 3 < n) {
        float4 v = *(const float4*)(in + i);
        ushort4 o;
        o.x = f2b(v.x); o.y = f2b(v.y); o.z = f2b(v.z); o.w = f2b(v.w);
        *(ushort4*)(out + i) = o;
    }
}

// both weight matrices in one dispatch
__global__ __launch_bounds__(256) void cvt_w2(const float* __restrict__ Wu,
                                              const float* __restrict__ Wf,
                                              ushort* __restrict__ Wub,
                                              ushort* __restrict__ Wfb, int n) {
    int i = (blockIdx.x * 256 + threadIdx.x) * 4;
    const float* in = (i < n) ? Wu : Wf;
    ushort* out = (i < n) ? Wub : Wfb;
    int j = (i < n) ? i : i - n;
    float4 v = *(const float4*)(in + j);
    ushort4 o;
    o.x = f2b(v.x); o.y = f2b(v.y); o.z = f2b(v.z); o.w = f2b(v.w);
    *(ushort4*)(out + j) = o;
}

// C = A (MxK, row-major bf16) * Bm^T (Bm is NxK row-major bf16) + bias
//
// 256x256 tile, BK=64, 512 threads = 8 waves (2M x 4N), per-wave 128x64 out.
// 4-phase-per-K-tile schedule (the m201 8-phase template, one BK=64 tile per
// 4 phases). Phase p computes quadrant (mq,nq) of the wave's output over K=64:
//   p1=(0,0) p2=(0,1) p3=(1,0) p4=(1,1)
// with 16 MFMA per phase. Fragments are read ONCE and live across phases:
//   p1 reads af(h0)[8] + bf0[4], p2 reads bf1[4], p3 reads af(h1)[8], p4 none.
//
// LDS regions grouped by death-order (slot s = tile&1, each region 16 KB):
//   A half h: block rows {h*64..h*64+63} U {128+h*64..128+h*64+63}
//             (all rows wave wm reads for mq=h)  -> last ds_read at phase 1/3
//   B half h: Bm rows {wn*64+h*32 .. +31 for all wn} -> last ds_read at 1/2
// Stage schedule (2 gl2lds per phase, 2 tiles deep, race-free because each
// target region's last read completed before a barrier preceding the issue):
//   p1: (u+1) A-h1 -> slot s^1   p2: (u+1) B-n1 -> slot s^1
//   p3: (u+2) A-h0 -> slot s     p4: (u+2) B-n0 -> slot s
// One counted vmcnt(4) per tile (never 0 in main loop): guarantees tile u+1
// fully landed while the 2 newest half-regions stay in flight. vmcnt(0) only
// at u == nt-2 to cover the tail.
//
// K-granule XOR swizzle (slot granule g of LDS row r holds logical granule
// g^(r&7)), applied on the GLOBAL address side of the DMA; verified
// conflict-free in prior rounds (SQ_LDS_BANK_CONFLICT = 0).
template <bool OUT_BF16>
__global__ __launch_bounds__(512, 2) void gemm_bt(const ushort* __restrict__ A,
                                                  const ushort* __restrict__ Bm,
                                                  const float* __restrict__ bias,
                                                  void* __restrict__ C,
                                                  int M, int N, int K) {
    __shared__ ushort As[2 * 16384];   // 64 KB: slot*16384 + h*8192 + line*4096 + row*64
    __shared__ ushort Bs[2 * 16384];   // 64 KB

    const int tid = threadIdx.x;
    const int lane = tid & 63;
    const int wave = tid >> 6;                 // 0..7
    const int nbn = N >> 8;                    // 4
    // XCD-aware mapping: XCD = blockIdx % 8; bn fastest within an XCD.
    const int xcd = blockIdx.x & 7;
    const int g = blockIdx.x >> 3;
    const int bpx = (gridDim.x >> 3) / nbn;
    const int bm = xcd * bpx + g / nbn;
    const int bn = g % nbn;
    const int wm = wave >> 2, wn = wave & 3;   // 2 x 4 wave grid
    const int l15 = lane & 15, quad = lane >> 4;

    // ---- staging addresses (per-lane global, wave-uniform LDS) ----
    const int qa = wave * 8 + (lane >> 3);            // row within a 64-row line
    const int sg = ((lane & 7) ^ (qa & 7)) * 8;       // swizzled k-granule (elems)
    const ushort* Ag = A + (size_t)(bm * 256 + qa) * K + sg;
    const int brow0 = bn * 256 + ((qa >> 5) << 6) + (qa & 31);
    const ushort* Bg = Bm + (size_t)brow0 * K + sg;
    const int ldst = wave * 512;                       // wave-uniform elems

#define SA(v, h, c)                                                             \
    gl2lds16(Ag + (size_t)((c) * 128 + (h) * 64) * K + (size_t)(v) * 64,        \
             As + (((v) & 1) * 16384 + (h) * 8192 + (c) * 4096 + ldst))
#define SB(v, h, d)                                                             \
    gl2lds16(Bg + (size_t)((d) * 128 + (h) * 32) * K + (size_t)(v) * 64,        \
             Bs + (((v) & 1) * 16384 + (h) * 8192 + (d) * 4096 + ldst))

    // ---- compute-side per-thread constants ----
    const int aro = (wm * 64 + l15) * 64;   // + h*8192 + i*1024 (+slot)
    const int bro = (wn * 32 + l15) * 64;   // + h*8192 + j*1024 (+slot)
    const int sw = l15 & 7;
    const int k0off = (quad ^ sw) * 8;
    const int k1off = ((4 + quad) ^ sw) * 8;

    f32x4 acc[8][4];
#pragma unroll
    for (int i = 0; i < 8; ++i)
#pragma unroll
        for (int j = 0; j < 4; ++j) acc[i][j] = (f32x4){0.f, 0.f, 0.f, 0.f};

    bf16x8 af[4][2], bf0[2][2], bf1[2][2];

#define READ_AF(h)                                                              \
    do {                                                                        \
        _Pragma("unroll") for (int i = 0; i < 4; ++i) {                         \
            af[i][0] = *(const bf16x8*)(Asl + (h) * 8192 + i * 1024 + aro + k0off); \
            af[i][1] = *(const bf16x8*)(Asl + (h) * 8192 + i * 1024 + aro + k1off); \
        }                                                                       \
    } while (0)
#define READ_BF(dst, h)                                                         \
    do {                                                                        \
        _Pragma("unroll") for (int j = 0; j < 2; ++j) {                         \
            dst[j][0] = *(const bf16x8*)(Bsl + (h) * 8192 + j * 1024 + bro + k0off); \
            dst[j][1] = *(const bf16x8*)(Bsl + (h) * 8192 + j * 1024 + bro + k1off); \
        }                                                                       \
    } while (0)
#define MFMA_Q(mq, nq, bfr)                                                     \
    do {                                                                        \
        __builtin_amdgcn_s_setprio(1);                                          \
        _Pragma("unroll") for (int kk = 0; kk < 2; ++kk)                        \
        _Pragma("unroll") for (int i = 0; i < 4; ++i)                           \
        _Pragma("unroll") for (int j = 0; j < 2; ++j)                           \
            acc[(mq) * 4 + i][(nq) * 2 + j] = __builtin_amdgcn_mfma_f32_16x16x32_bf16( \
                af[i][kk], bfr[j][kk], acc[(mq) * 4 + i][(nq) * 2 + j], 0, 0, 0); \
        __builtin_amdgcn_s_setprio(0);                                          \
    } while (0)

    const int nt = K >> 6;   // 16

    // ---- prologue: tile 0 complete (8 lines) + tile 1's A-h0/B-n0 (4 lines) ----
    SA(0, 0, 0); SA(0, 0, 1); SB(0, 0, 0); SB(0, 0, 1);
    SA(0, 1, 0); SA(0, 1, 1); SB(0, 1, 0); SB(0, 1, 1);
    SA(1, 0, 0); SA(1, 0, 1); SB(1, 0, 0); SB(1, 0, 1);
    asm volatile("s_waitcnt vmcnt(4)" ::: "memory");   // tile 0's 8 landed
    __builtin_amdgcn_s_barrier();

    for (int u = 0; u < nt; ++u) {
        const ushort* Asl = As + (u & 1) * 16384;
        const ushort* Bsl = Bs + (u & 1) * 16384;

        // ---- phase 1: quadrant (0,0) ----
        READ_AF(0);
        READ_BF(bf0, 0);
        if (u + 1 < nt) { SA(u + 1, 1, 0); SA(u + 1, 1, 1); }
        asm volatile("s_waitcnt lgkmcnt(8)" ::: "memory");
        __builtin_amdgcn_s_barrier();
        asm volatile("s_waitcnt lgkmcnt(0)" ::: "memory");
        MFMA_Q(0, 0, bf0);
        __builtin_amdgcn_s_barrier();

        // ---- phase 2: quadrant (0,1) ----
        READ_BF(bf1, 1);
        if (u + 1 < nt) { SB(u + 1, 1, 0); SB(u + 1, 1, 1); }
        __builtin_amdgcn_s_barrier();
        asm volatile("s_waitcnt lgkmcnt(0)" ::: "memory");
        MFMA_Q(0, 1, bf1);
        __builtin_amdgcn_s_barrier();

        // ---- phase 3: quadrant (1,0) ----
        READ_AF(1);
        if (u + 2 < nt) { SA(u + 2, 0, 0); SA(u + 2, 0, 1); }
        __builtin_amdgcn_s_barrier();
        asm volatile("s_waitcnt lgkmcnt(0)" ::: "memory");
        MFMA_Q(1, 0, bf0);
        __builtin_amdgcn_s_barrier();

        // ---- phase 4: quadrant (1,1) ----
        if (u + 2 < nt) { SB(u + 2, 0, 0); SB(u + 2, 0, 1); }
        __builtin_amdgcn_s_barrier();
        asm volatile("s_waitcnt lgkmcnt(0)" ::: "memory");
        MFMA_Q(1, 1, bf1);
        if (u < nt - 2)
            asm volatile("s_waitcnt vmcnt(4)" ::: "memory");  // tile u+1 landed
        else
            asm volatile("s_waitcnt vmcnt(0)" ::: "memory");  // tail drain
        __builtin_amdgcn_s_barrier();
    }
#undef SA
#undef SB
#undef READ_AF
#undef READ_BF
#undef MFMA_Q

    // epilogue: C/D layout col=lane&15, row=quad*4+reg  [verified m89/m91]
    // acc[i8][j4]: row off = i8*16 (== (i8>>2)*64 + (i8&3)*16), col off = j4*16
    const int gm0 = bm * 256 + wm * 128;
    const int gn0 = bn * 256 + wn * 64;
    float bv[4];
#pragma unroll
    for (int j = 0; j < 4; ++j) bv[j] = bias[gn0 + j * 16 + l15];
#pragma unroll
    for (int i = 0; i < 8; ++i) {
#pragma unroll
        for (int j = 0; j < 4; ++j) {
            const int col = gn0 + j * 16 + l15;
#pragma unroll
            for (int r = 0; r < 4; ++r) {
                const int row = gm0 + i * 16 + quad * 4 + r;
                float v = acc[i][j][r] + bv[j];
                if (OUT_BF16)
                    ((ushort*)C)[(size_t)row * N + col] = f2b(v);
                else
                    ((float*)C)[(size_t)row * N + col] = v;
            }
        }
    }
}

// Pass A: per (b, chunk) compute affine (A_c scalar, B_c vector of D)
// 4-step batched loads so 4+ ushort4 loads are in flight per wave.
__global__ __launch_bounds__(256) void scan_partial(const ushort* __restrict__ upd,
                                                    const float* __restrict__ mask,
                                                    const float* __restrict__ dp,
                                                    float* __restrict__ Bc,
                                                    float* __restrict__ Ac,
                                                    int S, int D, int C) {
    const int c = blockIdx.x % C;
    const int b = blockIdx.x / C;
    const int L = S / C;
    const int d0 = threadIdx.x * 4;
    const float decay = 1.f / (1.f + expf(-dp[0]));
    const ushort* up = upd + ((size_t)b * S + (size_t)c * L) * D + d0;
    const float* mp = mask + (size_t)b * S + (size_t)c * L;
    float aA = 1.f;
    float b0 = 0.f, b1 = 0.f, b2 = 0.f, b3 = 0.f;
    for (int s0 = 0; s0 < L; s0 += 4) {
        float4 mv = *(const float4*)(mp + s0);
        ushort4 u0 = *(const ushort4*)(up + (size_t)(s0 + 0) * D);
        ushort4 u1 = *(const ushort4*)(up + (size_t)(s0 + 1) * D);
        ushort4 u2 = *(const ushort4*)(up + (size_t)(s0 + 2) * D);
        ushort4 u3 = *(const ushort4*)(up + (size_t)(s0 + 3) * D);
        float m, a;
        m = mv.x; a = m * decay + (1.f - m); aA *= a;
        b0 = a * b0 + m * b2f(u0.x); b1 = a * b1 + m * b2f(u0.y);
        b2 = a * b2 + m * b2f(u0.z); b3 = a * b3 + m * b2f(u0.w);
        m = mv.y; a = m * decay + (1.f - m); aA *= a;
        b0 = a * b0 + m * b2f(u1.x); b1 = a * b1 + m * b2f(u1.y);
        b2 = a * b2 + m * b2f(u1.z); b3 = a * b3 + m * b2f(u1.w);
        m = mv.z; a = m * decay + (1.f - m); aA *= a;
        b0 = a * b0 + m * b2f(u2.x); b1 = a * b1 + m * b2f(u2.y);
        b2 = a * b2 + m * b2f(u2.z); b3 = a * b3 + m * b2f(u2.w);
        m = mv.w; a = m * decay + (1.f - m); aA *= a;
        b0 = a * b0 + m * b2f(u3.x); b1 = a * b1 + m * b2f(u3.y);
        b2 = a * b2 + m * b2f(u3.z); b3 = a * b3 + m * b2f(u3.w);
    }
    *(float4*)(Bc + (size_t)blockIdx.x * D + d0) = make_float4(b0, b1, b2, b3);
    if (threadIdx.x == 0) Ac[blockIdx.x] = aA;
}

// Pass B: serial prefix over C chunks per (b,d) chain; writes incoming state per chunk.
__global__ __launch_bounds__(256) void scan_prefix(const float* __restrict__ Ac,
                                                   const float* __restrict__ Bc,
                                                   float* __restrict__ Mn, int D, int C) {
    int gid = blockIdx.x * 256 + threadIdx.x;  // over B*D
    int b = gid / D;
    int d = gid - b * D;
    float mem = 0.f;
    for (int c = 0; c < C; c += 4) {
        float4 av = *(const float4*)(Ac + b * C + c);
        size_t i0 = ((size_t)(b * C + c)) * D + d;
        float q0 = Bc[i0];
        float q1 = Bc[i0 + D];
        float q2 = Bc[i0 + 2 * (size_t)D];
        float q3 = Bc[i0 + 3 * (size_t)D];
        Mn[i0] = mem;                    mem = av.x * mem + q0;
        Mn[i0 + D] = mem;                mem = av.y * mem + q1;
        Mn[i0 + 2 * (size_t)D] = mem;    mem = av.z * mem + q2;
        Mn[i0 + 3 * (size_t)D] = mem;    mem = av.w * mem + q3;
    }
}

// Pass C: replay each chunk from its incoming state, write mem_seq (bf16)
__global__ __launch_bounds__(256) void scan_final(const ushort* __restrict__ upd,
                                                  const float* __restrict__ mask,
                                                  const float* __restrict__ dp,
                                                  const float* __restrict__ Mn,
                                                  ushort* __restrict__ ms,
                                                  int S, int D, int C) {
    const int c = blockIdx.x % C;
    const int b = blockIdx.x / C;
    const int L = S / C;
    const int d0 = threadIdx.x * 4;
    const float decay = 1.f / (1.f + expf(-dp[0]));
    const ushort* up = upd + ((size_t)b * S + (size_t)c * L) * D + d0;
    ushort* op = ms + ((size_t)b * S + (size_t)c * L) * D + d0;
    const float* mp = mask + (size_t)b * S + (size_t)c * L;
    float4 m0 = *(const float4*)(Mn + (size_t)blockIdx.x * D + d0);
    float v0 = m0.x, v1 = m0.y, v2 = m0.z, v3 = m0.w;
    for (int s0 = 0; s0 < L; s0 += 4) {
        float4 mv = *(const float4*)(mp + s0);
        ushort4 u0 = *(const ushort4*)(up + (size_t)(s0 + 0) * D);
        ushort4 u1 = *(const ushort4*)(up + (size_t)(s0 + 1) * D);
        ushort4 u2 = *(const ushort4*)(up + (size_t)(s0 + 2) * D);
        ushort4 u3 = *(const ushort4*)(up + (size_t)(s0 + 3) * D);
        float m, a;
        ushort4 o;
        m = mv.x; a = m * decay + (1.f - m);
        v0 = a * v0 + m * b2f(u0.x); v1 = a * v1 + m * b2f(u0.y);
        v2 = a * v2 + m * b2f(u0.z); v3 = a * v3 + m * b2f(u0.w);
        o.x = f2b(v0); o.y = f2b(v1); o.z = f2b(v2); o.w = f2b(v3);
        *(ushort4*)(op + (size_t)(s0 + 0) * D) = o;
        m = mv.y; a = m * decay + (1.f - m);
        v0 = a * v0 + m * b2f(u1.x); v1 = a * v1 + m * b2f(u1.y);
        v2 = a * v2 + m * b2f(u1.z); v3 = a * v3 + m * b2f(u1.w);
        o.x = f2b(v0); o.y = f2b(v1); o.z = f2b(v2); o.w = f2b(v3);
        *(ushort4*)(op + (size_t)(s0 + 1) * D) = o;
        m = mv.z; a = m * decay + (1.f - m);
        v0 = a * v0 + m * b2f(u2.x); v1 = a * v1 + m * b2f(u2.y);
        v2 = a * v2 + m * b2f(u2.z); v3 = a * v3 + m * b2f(u2.w);
        o.x = f2b(v0); o.y = f2b(v1); o.z = f2b(v2); o.w = f2b(v3);
        *(ushort4*)(op + (size_t)(s0 + 2) * D) = o;
        m = mv.w; a = m * decay + (1.f - m);
        v0 = a * v0 + m * b2f(u3.x); v1 = a * v1 + m * b2f(u3.y);
        v2 = a * v2 + m * b2f(u3.z); v3 = a * v3 + m * b2f(u3.w);
        o.x = f2b(v0); o.y = f2b(v1); o.z = f2b(v2); o.w = f2b(v3);
        *(ushort4*)(op + (size_t)(s0 + 3) * D) = o;
    }
}

extern "C" void kernel_launch(void* const* d_in, const int* in_sizes, int n_in,
                              void* d_out, int out_size, void* d_ws, size_t ws_size,
                              hipStream_t stream) {
    const float* x    = (const float*)d_in[0];
    const float* mask = (const float*)d_in[1];
    const float* Wu   = (const float*)d_in[2];
    const float* bu   = (const float*)d_in[3];
    const float* Wf   = (const float*)d_in[4];
    const float* bfv  = (const float*)d_in[5];
    const float* dp   = (const float*)d_in[6];

    const int B = PB, S = PS, D = PD;
    const int M = B * S;          // 32768
    const int C = 128;            // scan chunks; L = 32

    // workspace layout (bytes): total ~204 MB
    char* ws = (char*)d_ws;
    ushort* xb   = (ushort*)(ws);                 // 64 MB  bf16 x
    ushort* updb = (ushort*)(ws + 67108864);      // 64 MB  bf16 upd
    ushort* memb = (ushort*)(ws + 134217728);     // 64 MB  bf16 mem_seq
    ushort* Wub  = (ushort*)(ws + 201326592);     // 2 MB
    ushort* Wfb  = (ushort*)(ws + 203423744);     // 2 MB
    float*  Bc   = (float*)(ws + 205520896);      // 4 MB   B*C*D
    float*  Mn   = (float*)(ws + 209715200);      // 4 MB   B*C*D
    float*  Ac   = (float*)(ws + 213909504);      // 4 KB   B*C

    const int nx = B * S * D;
    cvt_f32_bf16<<<nx / 1024, 256, 0, stream>>>(x, xb, nx);
    cvt_w2<<<(2 * D * D) / 1024, 256, 0, stream>>>(Wu, Wf, Wub, Wfb, D * D);

    dim3 g1((M / 256) * (D / 256));  // 512 blocks, %8 == 0 for XCD swizzle
    gemm_bt<true><<<g1, 512, 0, stream>>>(xb, Wub, bu, (void*)updb, M, D, D);

    scan_partial<<<B * C, 256, 0, stream>>>(updb, mask, dp, Bc, Ac, S, D, C);
    scan_prefix<<<(B * D) / 256, 256, 0, stream>>>(Ac, Bc, Mn, D, C);
    scan_final<<<B * C, 256, 0, stream>>>(updb, mask, dp, Mn, memb, S, D, C);

    gemm_bt<false><<<g1, 512, 0, stream>>>(memb, Wfb, bfv, d_out, M, D, D);
}